// Round 13
// baseline (7220.739 us; speedup 1.0000x reference)
//
#include <hip/hip_runtime.h>

#define V_ 32000
#define D_ 512
#define R_ 512
#define E_ 512
#define B_ 32
#define T_ 64
#define S_ 64
#define BT_ (B_ * T_)   // 2048
#define G3_ (3 * R_)    // 1536

typedef _Float16 f16;
typedef _Float16 f16x2 __attribute__((ext_vector_type(2)));
typedef _Float16 f16x8 __attribute__((ext_vector_type(8)));
typedef __bf16 bf16x8 __attribute__((ext_vector_type(8)));
typedef float f32x4 __attribute__((ext_vector_type(4)));

#define PAIR(v, i) (f16x2){(v)[2*(i)], (v)[2*(i)+1]}

__device__ __forceinline__ float fdot2_(f16x2 a, f16x2 b, float c) {
    return __builtin_amdgcn_fdot2(a, b, c, false);
}
__device__ __forceinline__ float sigmoidf_(float x) {
    return 1.0f / (1.0f + __expf(-x));
}

// ---------------- fp32 -> bf16 convert ----------------
__global__ __launch_bounds__(256) void k_convert_bf16(const float* __restrict__ src,
                                                      __bf16* __restrict__ dst, int n8) {
    int i = blockIdx.x * 256 + threadIdx.x;
    if (i >= n8) return;
    float4 a = *(const float4*)&src[(size_t)i * 8];
    float4 b = *(const float4*)&src[(size_t)i * 8 + 4];
    bf16x8 o;
    o[0] = (__bf16)a.x; o[1] = (__bf16)a.y; o[2] = (__bf16)a.z; o[3] = (__bf16)a.w;
    o[4] = (__bf16)b.x; o[5] = (__bf16)b.y; o[6] = (__bf16)b.z; o[7] = (__bf16)b.w;
    *(bf16x8*)&dst[(size_t)i * 8] = o;
}

// ---------------- fp32 -> f16 convert ----------------
__global__ __launch_bounds__(256) void k_convert_f16(const float* __restrict__ src,
                                                     f16* __restrict__ dst, int n8) {
    int i = blockIdx.x * 256 + threadIdx.x;
    if (i >= n8) return;
    float4 a = *(const float4*)&src[(size_t)i * 8];
    float4 b = *(const float4*)&src[(size_t)i * 8 + 4];
    f16x8 o;
    o[0] = (f16)a.x; o[1] = (f16)a.y; o[2] = (f16)a.z; o[3] = (f16)a.w;
    o[4] = (f16)b.x; o[5] = (f16)b.y; o[6] = (f16)b.z; o[7] = (f16)b.w;
    *(f16x8*)&dst[(size_t)i * 8] = o;
}

// ---------------- gather embedding rows (bf16) ----------------
__global__ __launch_bounds__(256) void k_gather_emb(const int* __restrict__ trg,
                                                    const __bf16* __restrict__ embW,
                                                    __bf16* __restrict__ dst) {
    int id = blockIdx.x * 256 + threadIdx.x;
    int bt = id >> 6, c = id & 63;
    int tok = trg[bt];
    *(uint4*)&dst[(size_t)bt * 512 + c * 8] = *(const uint4*)&embW[(size_t)tok * 512 + c * 8];
}

// ---------------- bf16 MFMA GEMM: C = A[M,K] * B^T[N,K] (+bias) ----------------
// mode 0: out[row*N+col]; mode 1: out[((row&63)*B_ + (row>>6))*G3_ + col]  (gxe [t][b][j3])
__global__ __launch_bounds__(256) void k_gemm_bf16(const __bf16* __restrict__ A,
                                                   const __bf16* __restrict__ B,
                                                   const float* __restrict__ bias,
                                                   float* __restrict__ out,
                                                   int M, int N, int K, int lda, int ldb,
                                                   int mode) {
    __shared__ __bf16 lA[128 * 40];
    __shared__ __bf16 lB[128 * 40];
    const int Mt = M >> 7;
    const int mt = blockIdx.x % Mt, nt = blockIdx.x / Mt;
    const int m0 = mt << 7, n0 = nt << 7;
    const int tid = threadIdx.x;
    const int w = tid >> 6, ln = tid & 63;
    const int wm = w >> 1, wn = w & 1;

    f32x4 acc[4][4];
#pragma unroll
    for (int mi = 0; mi < 4; ++mi)
#pragma unroll
        for (int ni = 0; ni < 4; ++ni) acc[mi][ni] = (f32x4){0.f, 0.f, 0.f, 0.f};

    const int k0 = (ln >> 4) * 8, rr = ln & 15;

    for (int kk = 0; kk < K; kk += 32) {
        __syncthreads();
#pragma unroll
        for (int p = 0; p < 2; ++p) {
            int i = p * 256 + tid;
            int r = i >> 2, q = i & 3;
            *(uint4*)&lA[r * 40 + q * 8] = *(const uint4*)&A[(size_t)(m0 + r) * lda + kk + q * 8];
            *(uint4*)&lB[r * 40 + q * 8] = *(const uint4*)&B[(size_t)(n0 + r) * ldb + kk + q * 8];
        }
        __syncthreads();
        bf16x8 af[4], bf[4];
#pragma unroll
        for (int mi = 0; mi < 4; ++mi) af[mi] = *(bf16x8*)&lA[(wm * 64 + mi * 16 + rr) * 40 + k0];
#pragma unroll
        for (int ni = 0; ni < 4; ++ni) bf[ni] = *(bf16x8*)&lB[(wn * 64 + ni * 16 + rr) * 40 + k0];
#pragma unroll
        for (int mi = 0; mi < 4; ++mi)
#pragma unroll
            for (int ni = 0; ni < 4; ++ni)
                acc[mi][ni] = __builtin_amdgcn_mfma_f32_16x16x32_bf16(af[mi], bf[ni], acc[mi][ni], 0, 0, 0);
    }

    const int rq = ln >> 4;
#pragma unroll
    for (int mi = 0; mi < 4; ++mi) {
#pragma unroll
        for (int ni = 0; ni < 4; ++ni) {
            int col = n0 + wn * 64 + ni * 16 + rr;
            float bv = bias ? bias[col] : 0.f;
#pragma unroll
            for (int reg = 0; reg < 4; ++reg) {
                int row = m0 + wm * 64 + mi * 16 + rq * 4 + reg;
                float v = acc[mi][ni][reg] + bv;
                if (mode == 0) {
                    out[(size_t)row * N + col] = v;
                } else {
                    int bb = row >> 6, tt = row & 63;
                    out[((size_t)tt * B_ + bb) * G3_ + col] = v;
                }
            }
        }
    }
}

// ---------------- weight packing (one-time) ----------------
__global__ __launch_bounds__(256) void k_pack_gates(const float* __restrict__ Wih,
                                                    const float* __restrict__ Whh,
                                                    f16* __restrict__ Wg) {
    int idx = blockIdx.x * 256 + threadIdx.x;  // 1536*1024
    int j3 = idx >> 10, k = idx & 1023;
    float v = (k < 512) ? Wih[(size_t)j3 * 1024 + 512 + k] : Whh[(size_t)j3 * 512 + (k - 512)];
    Wg[idx] = (f16)v;
}
__global__ __launch_bounds__(256) void k_pack_ewT(const float* __restrict__ ew, f16* __restrict__ ewT) {
    int idx = blockIdx.x * 256 + threadIdx.x;  // 32*512*64
    int b = idx >> 15, d = (idx >> 6) & 511, s = idx & 63;
    ewT[idx] = (f16)ew[((size_t)b * 64 + s) * 512 + d];
}
// x16[0] = [o=0(0..511) | h=init_h(512..1023)] f16 per b; hbuf[0] = init_h f32
__global__ __launch_bounds__(256) void k_init_state(const float* __restrict__ init_h,
                                                    f16* __restrict__ x16,
                                                    float* __restrict__ hbuf) {
    int idx = blockIdx.x * 256 + threadIdx.x;  // 32*1024
    int b = idx >> 10, k = idx & 1023;
    if (k < 512) {
        x16[idx] = (f16)0.f;
    } else {
        float v = init_h[(size_t)b * 512 + (k - 512)];
        x16[idx] = (f16)v;
        hbuf[(size_t)b * 512 + (k - 512)] = v;
    }
}

// ---------------- merged step: GRU + attention + output, one kernel per t ----------------
// 32 wgs (wg = b) x 1024 thr. Phase A: thread=(j=tid>>1, half=tid&1) computes gates
// via f16 fdot2; h(t) kept in LDS for phase B (no cross-wg traffic inside a step).
__global__ __launch_bounds__(1024, 1) void k_step(
    const f16* __restrict__ Wg, const f16* __restrict__ whf16,
    const f16* __restrict__ epf16, const f16* __restrict__ encWcT,
    const float* __restrict__ gxe_t,   // [b][1536] for this t
    const float* __restrict__ bhh,
    const float* __restrict__ mask, const float* __restrict__ bh, const float* __restrict__ bc,
    const f16* __restrict__ x_in, f16* __restrict__ x_out,
    const float* __restrict__ h_in, float* __restrict__ h_out,
    __bf16* __restrict__ obf, int t) {
    __shared__ __align__(16) f16 xl[1024];    // [o(t-1) | h(t-1)] for this b
    __shared__ __align__(16) f16 hl16[512];   // h(t) f16
    __shared__ float sc_[64];
    __shared__ float s_af[64];
    __shared__ f16x2 a2l[32];
    const int tid = threadIdx.x;
    const int b = blockIdx.x;

    // stage x_in[b] (2 KB)
    if (tid < 128) {
        *(uint4*)(xl + tid * 8) = *(const uint4*)(x_in + (size_t)b * 1024 + tid * 8);
    }
    __syncthreads();

    // ---- Phase A: gates + h_new ----
    {
        const int j = tid >> 1, half = tid & 1;
        const f16* xb = xl + half * 512;
        const f16* wr = Wg + (size_t)(j) * 1024 + half * 512;
        const f16* wz = Wg + (size_t)(512 + j) * 1024 + half * 512;
        const f16* wn = Wg + (size_t)(1024 + j) * 1024 + half * 512;
        float ar = 0.f, az = 0.f, an = 0.f;
#pragma unroll 4
        for (int c = 0; c < 64; ++c) {
            f16x8 xv = *(const f16x8*)(xb + c * 8);
            f16x8 wrv = *(const f16x8*)(wr + c * 8);
            f16x8 wzv = *(const f16x8*)(wz + c * 8);
            f16x8 wnv = *(const f16x8*)(wn + c * 8);
#pragma unroll
            for (int q = 0; q < 4; ++q) {
                f16x2 xp = PAIR(xv, q);
                ar = fdot2_(xp, PAIR(wrv, q), ar);
                az = fdot2_(xp, PAIR(wzv, q), az);
                an = fdot2_(xp, PAIR(wnv, q), an);
            }
        }
        float aro = __shfl_xor(ar, 1);
        float azo = __shfl_xor(az, 1);
        float ano = __shfl_xor(an, 1);
        if (half == 0) {
            const float* gp = gxe_t + (size_t)b * G3_;
            float gr = gp[j];
            float gz = gp[512 + j];
            float gn = gp[1024 + j];
            float r = sigmoidf_(gr + bhh[j] + ar + aro);
            float z = sigmoidf_(gz + bhh[512 + j] + az + azo);
            float n = tanhf((gn + ar * 0.f + an) + r * (bhh[1024 + j] + ano));
            float hp = h_in[(size_t)b * 512 + j];
            float hnew = (1.f - z) * n + z * hp;
            h_out[(size_t)b * 512 + j] = hnew;
            x_out[(size_t)b * 1024 + 512 + j] = (f16)hnew;
            hl16[j] = (f16)hnew;
        }
    }
    __syncthreads();

    // ---- Phase B: scores + softmax + output ----
    // scores: s = tid>>4 (0..63), q = tid&15 (32-f16 chunk each)
    {
        int s = tid >> 4, q = tid & 15;
        const f16* ep = epf16 + ((size_t)(b * 64 + s)) * 512 + q * 32;
        const f16* hh = hl16 + q * 32;
        float a = 0.f;
#pragma unroll
        for (int c = 0; c < 4; ++c) {
            f16x8 ev = *(const f16x8*)(ep + c * 8);
            f16x8 xv = *(const f16x8*)(hh + c * 8);
#pragma unroll
            for (int qq = 0; qq < 4; ++qq) a = fdot2_(PAIR(ev, qq), PAIR(xv, qq), a);
        }
        a += __shfl_xor(a, 1);
        a += __shfl_xor(a, 2);
        a += __shfl_xor(a, 4);
        a += __shfl_xor(a, 8);
        if (q == 0) sc_[s] = a;
    }
    __syncthreads();
    if (tid < 64) {
        float s = sc_[tid];
        s = (mask[b * 64 + tid] > 0.f) ? s : -1e9f;
        float m = s;
#pragma unroll
        for (int d = 1; d < 64; d <<= 1) m = fmaxf(m, __shfl_xor(m, d));
        float e = __expf(s - m);
        float sum = e;
#pragma unroll
        for (int d = 1; d < 64; d <<= 1) sum += __shfl_xor(sum, d);
        s_af[tid] = e / sum;
    }
    __syncthreads();
    if (tid < 32) {
        a2l[tid] = (f16x2){(f16)s_af[2 * tid], (f16)s_af[2 * tid + 1]};
    }
    __syncthreads();
    // output: d = tid>>1, h2 = tid&1 (256-f16 half of Wh row each)
    {
        const int d = tid >> 1, h2 = tid & 1;
        const f16* wrow = whf16 + (size_t)d * 512 + h2 * 256;
        const f16* hh = hl16 + h2 * 256;
        float uh = 0.f;
#pragma unroll 4
        for (int c = 0; c < 32; ++c) {
            f16x8 wv = *(const f16x8*)(wrow + c * 8);
            f16x8 xv = *(const f16x8*)(hh + c * 8);
#pragma unroll
            for (int qq = 0; qq < 4; ++qq) uh = fdot2_(PAIR(wv, qq), PAIR(xv, qq), uh);
        }
        float uho = __shfl_xor(uh, 1);
        if (h2 == 0) {
            float u = uh + uho + bh[d] + bc[d];
            const f16* ew = encWcT + ((size_t)b * 512 + d) * 64;
#pragma unroll
            for (int c = 0; c < 8; ++c) {
                f16x8 ev = *(const f16x8*)(ew + c * 8);
#pragma unroll
                for (int qq = 0; qq < 4; ++qq) u = fdot2_(PAIR(ev, qq), a2l[c * 4 + qq], u);
            }
            float o = tanhf(u);
            obf[((size_t)b * 64 + t) * 512 + d] = (__bf16)o;
            x_out[(size_t)b * 1024 + d] = (f16)o;
        }
    }
}

extern "C" void kernel_launch(void* const* d_in, const int* in_sizes, int n_in,
                              void* d_out, int out_size, void* d_ws, size_t ws_size,
                              hipStream_t stream) {
    const int* trg = (const int*)d_in[0];
    const float* enc = (const float*)d_in[1];
    const float* init_h = (const float*)d_in[2];
    const float* mask = (const float*)d_in[3];
    const float* embW = (const float*)d_in[4];
    const float* Wih = (const float*)d_in[5];
    const float* Whh = (const float*)d_in[6];
    const float* bih = (const float*)d_in[7];
    const float* bhh = (const float*)d_in[8];
    const float* Wa = (const float*)d_in[9];
    const float* Wh = (const float*)d_in[10];
    const float* bh = (const float*)d_in[11];
    const float* Wc = (const float*)d_in[12];
    const float* bc = (const float*)d_in[13];
    const float* blog = (const float*)d_in[14];
    float* out = (float*)d_out;

    char* w = (char*)d_ws;
    auto alloc = [&](size_t bytes) { char* p = w; w += (bytes + 255) & ~(size_t)255; return p; };
    __bf16* embW_bf = (__bf16*)alloc((size_t)V_ * D_ * 2);
    __bf16* Wih_bf  = (__bf16*)alloc((size_t)G3_ * 1024 * 2);
    __bf16* Wa_bf   = (__bf16*)alloc((size_t)R_ * E_ * 2);
    __bf16* Wc_bf   = (__bf16*)alloc((size_t)D_ * E_ * 2);
    __bf16* enc_bf  = (__bf16*)alloc((size_t)BT_ * E_ * 2);
    __bf16* emb_bf  = (__bf16*)alloc((size_t)BT_ * D_ * 2);
    float* gxe      = (float*)alloc((size_t)T_ * B_ * G3_ * 4);   // [t][b][1536]
    float* encproj  = (float*)alloc((size_t)BT_ * R_ * 4);
    float* encWc    = (float*)alloc((size_t)BT_ * D_ * 4);
    f16* Wg         = (f16*)alloc((size_t)G3_ * 1024 * 2);
    f16* whf16      = (f16*)alloc((size_t)512 * 512 * 2);
    f16* epf16      = (f16*)alloc((size_t)BT_ * 512 * 2);
    f16* encWcT     = (f16*)alloc((size_t)32 * 512 * 64 * 2);
    f16* x16        = (f16*)alloc((size_t)2 * 32 * 1024 * 2);
    float* hbuf     = (float*)alloc((size_t)2 * 32 * 512 * 4);
    __bf16* o_bf    = (__bf16*)alloc((size_t)BT_ * D_ * 2);

    // 1) converts
    k_convert_bf16<<<(V_ * D_ / 8 + 255) / 256, 256, 0, stream>>>(embW, embW_bf, V_ * D_ / 8);
    k_convert_bf16<<<(G3_ * 1024 / 8 + 255) / 256, 256, 0, stream>>>(Wih, Wih_bf, G3_ * 1024 / 8);
    k_convert_bf16<<<(R_ * E_ / 8 + 255) / 256, 256, 0, stream>>>(Wa, Wa_bf, R_ * E_ / 8);
    k_convert_bf16<<<(D_ * E_ / 8 + 255) / 256, 256, 0, stream>>>(Wc, Wc_bf, D_ * E_ / 8);
    k_convert_bf16<<<(BT_ * E_ / 8 + 255) / 256, 256, 0, stream>>>(enc, enc_bf, BT_ * E_ / 8);

    // 2) gather embedding rows
    k_gather_emb<<<(BT_ * 64) / 256, 256, 0, stream>>>(trg, embW_bf, emb_bf);

    // 3) gx_emb = emb @ W_ih[:, :512]^T + b_ih -> [t][b][j3]
    k_gemm_bf16<<<(BT_ / 128) * (G3_ / 128), 256, 0, stream>>>(
        emb_bf, Wih_bf, bih, gxe, BT_, G3_, 512, 512, 1024, 1);

    // 4) enc_proj = enc @ W_a^T; encWc = enc @ W_c^T
    k_gemm_bf16<<<(BT_ / 128) * (R_ / 128), 256, 0, stream>>>(
        enc_bf, Wa_bf, nullptr, encproj, BT_, R_, 512, 512, 512, 0);
    k_gemm_bf16<<<(BT_ / 128) * (D_ / 128), 256, 0, stream>>>(
        enc_bf, Wc_bf, nullptr, encWc, BT_, D_, 512, 512, 512, 0);

    // 5) pack weights / state
    k_pack_gates<<<(G3_ * 1024) / 256, 256, 0, stream>>>(Wih, Whh, Wg);
    k_convert_f16<<<(512 * 512 / 8 + 255) / 256, 256, 0, stream>>>(Wh, whf16, 512 * 512 / 8);
    k_convert_f16<<<(BT_ * 512 / 8 + 255) / 256, 256, 0, stream>>>(encproj, epf16, BT_ * 512 / 8);
    k_pack_ewT<<<(32 * 512 * 64) / 256, 256, 0, stream>>>(encWc, encWcT);
    k_init_state<<<(32 * 1024) / 256, 256, 0, stream>>>(init_h, x16, hbuf);

    // 6) recurrence: ONE kernel per step (64 launches)
    for (int t = 0; t < T_; ++t) {
        const f16* x_in = x16 + (size_t)(t & 1) * 32 * 1024;
        f16* x_out = x16 + (size_t)((t + 1) & 1) * 32 * 1024;
        const float* h_in = hbuf + (size_t)(t & 1) * 32 * 512;
        float* h_out = hbuf + (size_t)((t + 1) & 1) * 32 * 512;
        k_step<<<32, 1024, 0, stream>>>(Wg, whf16, epf16, encWcT,
                                        gxe + (size_t)t * B_ * G3_, bhh, mask, bh, bc,
                                        x_in, x_out, h_in, h_out, o_bf, t);
    }

    // 7) logits = o @ emb_W^T + b_logits
    k_gemm_bf16<<<(BT_ / 128) * (V_ / 128), 256, 0, stream>>>(
        o_bf, embW_bf, blog, out, BT_, V_, 512, 512, 512, 0);
}

// Round 15
// 1576.491 us; speedup vs baseline: 4.5803x; 4.5803x over previous
//
#include <hip/hip_runtime.h>

#define V_ 32000
#define D_ 512
#define R_ 512
#define E_ 512
#define B_ 32
#define T_ 64
#define S_ 64
#define BT_ (B_ * T_)   // 2048
#define G3_ (3 * R_)    // 1536

typedef _Float16 f16;
typedef _Float16 f16x2 __attribute__((ext_vector_type(2)));
typedef _Float16 f16x8 __attribute__((ext_vector_type(8)));
typedef __bf16 bf16x8 __attribute__((ext_vector_type(8)));
typedef float f32x4 __attribute__((ext_vector_type(4)));

#define PAIR(v, i) (f16x2){(v)[2*(i)], (v)[2*(i)+1]}

typedef __attribute__((address_space(3))) char lds_char;
typedef __attribute__((address_space(1))) const char glob_char;

__device__ __forceinline__ float fdot2_(f16x2 a, f16x2 b, float c) {
    return __builtin_amdgcn_fdot2(a, b, c, false);
}
__device__ __forceinline__ float sigmoidf_(float x) {
    return 1.0f / (1.0f + __expf(-x));
}

// ---------------- fused setup: all converts/packs/init in ONE kernel ----------------
#define SN0 ((size_t)V_ * D_)        // embW -> embW_bf
#define SN1 ((size_t)G3_ * 512)      // Wih[:, :512] -> Wih_bf [1536][512]
#define SN2 ((size_t)BT_ * E_)       // enc -> enc_bf
#define SN3 ((size_t)1024 * 512)     // [Wa; Wc] -> Wab_bf [1024][512]
#define SN4 ((size_t)G3_ * 1024)     // Wg f16 [1536][1024] = [Wih_o | Whh]
#define SN5 ((size_t)512 * 512)      // Wh -> whf16
#define SN6 ((size_t)32 * 1024)      // init x16[0], hbuf[0]

__device__ __forceinline__ void cvt8_bf16(const float* s, __bf16* d) {
    float4 a = *(const float4*)s, b = *(const float4*)(s + 4);
    bf16x8 o;
    o[0] = (__bf16)a.x; o[1] = (__bf16)a.y; o[2] = (__bf16)a.z; o[3] = (__bf16)a.w;
    o[4] = (__bf16)b.x; o[5] = (__bf16)b.y; o[6] = (__bf16)b.z; o[7] = (__bf16)b.w;
    *(bf16x8*)d = o;
}
__device__ __forceinline__ void cvt8_f16(const float* s, f16* d) {
    float4 a = *(const float4*)s, b = *(const float4*)(s + 4);
    f16x8 o;
    o[0] = (f16)a.x; o[1] = (f16)a.y; o[2] = (f16)a.z; o[3] = (f16)a.w;
    o[4] = (f16)b.x; o[5] = (f16)b.y; o[6] = (f16)b.z; o[7] = (f16)b.w;
    *(f16x8*)d = o;
}

__global__ __launch_bounds__(256) void k_setup(
    const float* __restrict__ embW, const float* __restrict__ Wih,
    const float* __restrict__ Whh, const float* __restrict__ enc,
    const float* __restrict__ Wa, const float* __restrict__ Wc,
    const float* __restrict__ Wh, const float* __restrict__ init_h,
    __bf16* __restrict__ embW_bf, __bf16* __restrict__ Wih_bf,
    __bf16* __restrict__ enc_bf, __bf16* __restrict__ Wab_bf,
    f16* __restrict__ Wg, f16* __restrict__ whf16,
    f16* __restrict__ x16, float* __restrict__ hbuf) {
    size_t e = ((size_t)blockIdx.x * 256 + threadIdx.x) * 8;
    if (e < SN0) { cvt8_bf16(embW + e, embW_bf + e); return; }
    e -= SN0;
    if (e < SN1) {
        size_t j3 = e >> 9, k = e & 511;
        cvt8_bf16(Wih + j3 * 1024 + k, Wih_bf + e);
        return;
    }
    e -= SN1;
    if (e < SN2) { cvt8_bf16(enc + e, enc_bf + e); return; }
    e -= SN2;
    if (e < SN3) {
        size_t r = e >> 9, k = e & 511;
        const float* s = (r < 512) ? (Wa + r * 512 + k) : (Wc + (r - 512) * 512 + k);
        cvt8_bf16(s, Wab_bf + e);
        return;
    }
    e -= SN3;
    if (e < SN4) {
        size_t j3 = e >> 10, k = e & 1023;
        const float* s = (k < 512) ? (Wih + j3 * 1024 + 512 + k) : (Whh + j3 * 512 + (k - 512));
        cvt8_f16(s, Wg + e);
        return;
    }
    e -= SN4;
    if (e < SN5) { cvt8_f16(Wh + e, whf16 + e); return; }
    e -= SN5;
    if (e < SN6) {
        size_t b = e >> 10, k = e & 1023;
        if (k < 512) {
            f16x8 z = {(f16)0.f, (f16)0.f, (f16)0.f, (f16)0.f,
                       (f16)0.f, (f16)0.f, (f16)0.f, (f16)0.f};
            *(f16x8*)(x16 + e) = z;
        } else {
            const float* s = init_h + b * 512 + (k - 512);
            cvt8_f16(s, x16 + e);
            *(float4*)(hbuf + b * 512 + (k - 512)) = *(const float4*)s;
            *(float4*)(hbuf + b * 512 + (k - 512) + 4) = *(const float4*)(s + 4);
        }
    }
}

// ---------------- bf16 MFMA GEMM with global_load_lds staging ----------------
// C = A[M,K] * B^T[N,K]. Linear LDS [128][32] per matrix (m97 pattern).
// mode 0: fp32 out[row*N+col] (+bias)
// mode 1: fp32 gxe scatter out[((row&63)*G3 + col)*B + (row>>6)] (+bias), A-row indirect via trg
// mode 2: f16 dual epilogue: col<512 -> out16a[row*512+col]; else out16b[((row>>6)*512+(col-512))*64 + (row&63)]
__global__ __launch_bounds__(256) void k_gemm_bf16(const __bf16* __restrict__ A,
                                                   const __bf16* __restrict__ Bm,
                                                   const float* __restrict__ bias,
                                                   float* __restrict__ out,
                                                   f16* __restrict__ out16a,
                                                   f16* __restrict__ out16b,
                                                   const int* __restrict__ trg,
                                                   int M, int N, int K, int lda, int ldb,
                                                   int mode) {
    __shared__ __bf16 lA[128 * 32];
    __shared__ __bf16 lB[128 * 32];
    const int Mt = M >> 7;
    const int mt = blockIdx.x % Mt, nt = blockIdx.x / Mt;
    const int m0 = mt << 7, n0 = nt << 7;
    const int tid = threadIdx.x;
    const int w = tid >> 6, ln = tid & 63;
    const int wm = w >> 1, wn = w & 1;

    // per-lane source rows (kk-independent): wave w stages rows h*64 + w*16 + (ln>>2)
    int arow[2], brow[2];
#pragma unroll
    for (int h = 0; h < 2; ++h) {
        int r = h * 64 + w * 16 + (ln >> 2);
        arow[h] = trg ? trg[m0 + r] : (m0 + r);
        brow[h] = n0 + r;
    }
    const int q8 = (ln & 3) * 8;

    f32x4 acc[4][4];
#pragma unroll
    for (int mi = 0; mi < 4; ++mi)
#pragma unroll
        for (int ni = 0; ni < 4; ++ni) acc[mi][ni] = (f32x4){0.f, 0.f, 0.f, 0.f};

    const int k0 = (ln >> 4) * 8, rr = ln & 15;

    for (int kk = 0; kk < K; kk += 32) {
        __syncthreads();
#pragma unroll
        for (int h = 0; h < 2; ++h) {
            const __bf16* srcA = A + (size_t)arow[h] * lda + kk + q8;
            const __bf16* srcB = Bm + (size_t)brow[h] * ldb + kk + q8;
            __bf16* dstA = lA + (size_t)(h * 64 + w * 16) * 32;
            __bf16* dstB = lB + (size_t)(h * 64 + w * 16) * 32;
            __builtin_amdgcn_global_load_lds((glob_char*)srcA, (lds_char*)dstA, 16, 0, 0);
            __builtin_amdgcn_global_load_lds((glob_char*)srcB, (lds_char*)dstB, 16, 0, 0);
        }
        __syncthreads();
        bf16x8 af[4], bf[4];
#pragma unroll
        for (int mi = 0; mi < 4; ++mi) af[mi] = *(bf16x8*)&lA[(wm * 64 + mi * 16 + rr) * 32 + k0];
#pragma unroll
        for (int ni = 0; ni < 4; ++ni) bf[ni] = *(bf16x8*)&lB[(wn * 64 + ni * 16 + rr) * 32 + k0];
#pragma unroll
        for (int mi = 0; mi < 4; ++mi)
#pragma unroll
            for (int ni = 0; ni < 4; ++ni)
                acc[mi][ni] = __builtin_amdgcn_mfma_f32_16x16x32_bf16(af[mi], bf[ni], acc[mi][ni], 0, 0, 0);
    }

    const int rq = ln >> 4;
#pragma unroll
    for (int mi = 0; mi < 4; ++mi) {
#pragma unroll
        for (int ni = 0; ni < 4; ++ni) {
            int col = n0 + wn * 64 + ni * 16 + rr;
            float bv = bias ? bias[col] : 0.f;
#pragma unroll
            for (int reg = 0; reg < 4; ++reg) {
                int row = m0 + wm * 64 + mi * 16 + rq * 4 + reg;
                float v = acc[mi][ni][reg] + bv;
                if (mode == 0) {
                    out[(size_t)row * N + col] = v;
                } else if (mode == 1) {
                    int bb = row >> 6, tt = row & 63;
                    out[((size_t)tt * G3_ + col) * B_ + bb] = v;
                } else {
                    if (col < 512) {
                        out16a[(size_t)row * 512 + col] = (f16)v;
                    } else {
                        out16b[(((size_t)(row >> 6) * 512 + (col - 512)) << 6) | (row & 63)] = (f16)v;
                    }
                }
            }
        }
    }
}

// ---------------- stepA: GRU gates + h_new (one launch per t) ----------------
// 128 wgs x 256 thr; wg owns 4 j. thread = (jl[4], half[2], b[32]).  [R12 verbatim]
__global__ __launch_bounds__(256) void k_stepA(
    const f16* __restrict__ Wg, const float* __restrict__ gp, const float* __restrict__ bhh,
    const f16* __restrict__ x_in, f16* __restrict__ x_out,
    const float* __restrict__ h_in, float* __restrict__ h_out) {
    __shared__ __align__(16) f16 x2l[32 * 1032];
    const int tid = threadIdx.x;
    const int wgid = blockIdx.x;
    const int bA = tid & 31;
    const int half = (tid >> 5) & 1;
    const int jl = tid >> 6;           // 0..3
    const int j = wgid * 4 + jl;

    // stage x_in (64KB = 4096 uint4) into LDS rows of 1032 f16
#pragma unroll
    for (int i = 0; i < 16; ++i) {
        int f = tid + i * 256;
        int row = f >> 7, col = f & 127;
        *(uint4*)(x2l + row * 1032 + col * 8) = *(const uint4*)(x_in + (size_t)f * 8);
    }
    __syncthreads();

    const f16* xb = x2l + bA * 1032 + half * 512;
    const f16* wr = Wg + (size_t)(j) * 1024 + half * 512;
    const f16* wz = Wg + (size_t)(512 + j) * 1024 + half * 512;
    const f16* wn = Wg + (size_t)(1024 + j) * 1024 + half * 512;
    float ar = 0.f, az = 0.f, an = 0.f;
#pragma unroll 4
    for (int c = 0; c < 64; ++c) {
        f16x8 xv = *(const f16x8*)(xb + c * 8);
        f16x8 wrv = *(const f16x8*)(wr + c * 8);
        f16x8 wzv = *(const f16x8*)(wz + c * 8);
        f16x8 wnv = *(const f16x8*)(wn + c * 8);
#pragma unroll
        for (int q = 0; q < 4; ++q) {
            f16x2 xp = PAIR(xv, q);
            ar = fdot2_(xp, PAIR(wrv, q), ar);
            az = fdot2_(xp, PAIR(wzv, q), az);
            an = fdot2_(xp, PAIR(wnv, q), an);
        }
    }
    float aro = __shfl_xor(ar, 32);
    float azo = __shfl_xor(az, 32);
    float ano = __shfl_xor(an, 32);
    float gr = gp[(size_t)j * 32 + bA];
    float gz = gp[(size_t)(512 + j) * 32 + bA];
    float gn = gp[(size_t)(1024 + j) * 32 + bA];
    float rpre = gr + bhh[j] + ar + aro;
    float zpre = gz + bhh[512 + j] + az + azo;
    float r = sigmoidf_(rpre);
    float z = sigmoidf_(zpre);
    float gxn = gn + (half ? ano : an);
    float ghn = bhh[1024 + j] + (half ? an : ano);
    float n = tanhf(gxn + r * ghn);
    float hp = h_in[(size_t)bA * 512 + j];
    float hnew = (1.f - z) * n + z * hp;
    if (half == 0) {
        h_out[(size_t)bA * 512 + j] = hnew;
        x_out[(size_t)bA * 1024 + 512 + j] = (f16)hnew;
    }
}

// ---------------- stepB: attention + output (one launch per t) ----------------
// 64 wgs x 256 thr; wg = (b, d-half).  [R12 verbatim]
__global__ __launch_bounds__(256) void k_stepB(
    const f16* __restrict__ whf16, const f16* __restrict__ epf16, const f16* __restrict__ encWcT,
    const float* __restrict__ mask, const float* __restrict__ bh, const float* __restrict__ bc,
    f16* __restrict__ x_out, __bf16* __restrict__ obf, int t) {
    __shared__ __align__(16) f16 hl16[512];
    __shared__ float sc_[64];
    __shared__ float s_af[64];
    __shared__ f16x2 a2l[32];
    const int tid = threadIdx.x;
    const int b = blockIdx.x >> 1, dh = blockIdx.x & 1;

    if (tid < 64) {
        *(uint4*)(hl16 + tid * 8) = *(const uint4*)(x_out + (size_t)b * 1024 + 512 + tid * 8);
    }
    __syncthreads();

    // scores: s = tid>>2 (0..63), q = tid&3 (128 f16 chunk each)
    {
        int s = tid >> 2, q = tid & 3;
        const f16* ep = epf16 + ((size_t)(b * 64 + s)) * 512 + q * 128;
        const f16* hh = hl16 + q * 128;
        float a = 0.f;
#pragma unroll
        for (int c = 0; c < 16; ++c) {
            f16x8 ev = *(const f16x8*)(ep + c * 8);
            f16x8 xv = *(const f16x8*)(hh + c * 8);
#pragma unroll
            for (int qq = 0; qq < 4; ++qq) a = fdot2_(PAIR(ev, qq), PAIR(xv, qq), a);
        }
        a += __shfl_xor(a, 1);
        a += __shfl_xor(a, 2);
        if (q == 0) sc_[s] = a;
    }
    __syncthreads();
    if (tid < 64) {
        float s = sc_[tid];
        s = (mask[b * 64 + tid] > 0.f) ? s : -1e9f;
        float m = s;
#pragma unroll
        for (int d = 1; d < 64; d <<= 1) m = fmaxf(m, __shfl_xor(m, d));
        float e = __expf(s - m);
        float sum = e;
#pragma unroll
        for (int d = 1; d < 64; d <<= 1) sum += __shfl_xor(sum, d);
        s_af[tid] = e / sum;
    }
    __syncthreads();
    if (tid < 32) {
        a2l[tid] = (f16x2){(f16)s_af[2 * tid], (f16)s_af[2 * tid + 1]};
    }
    __syncthreads();
    // u = b_h + b_c + Wh[d]·h + sum_s a_s encWc[b][s][d];  d = dh*256 + tid
    {
        const int d = dh * 256 + tid;
        float u = bh[d] + bc[d];
        const f16* wrow = whf16 + (size_t)d * 512;
#pragma unroll 8
        for (int c = 0; c < 64; ++c) {
            f16x8 wv = *(const f16x8*)(wrow + c * 8);
            f16x8 xv = *(const f16x8*)(hl16 + c * 8);
#pragma unroll
            for (int qq = 0; qq < 4; ++qq) u = fdot2_(PAIR(wv, qq), PAIR(xv, qq), u);
        }
        const f16* ew = encWcT + ((size_t)b * 512 + d) * 64;
#pragma unroll
        for (int c = 0; c < 8; ++c) {
            f16x8 ev = *(const f16x8*)(ew + c * 8);
#pragma unroll
            for (int qq = 0; qq < 4; ++qq) u = fdot2_(PAIR(ev, qq), a2l[c * 4 + qq], u);
        }
        float o = tanhf(u);
        obf[((size_t)b * 64 + t) * 512 + d] = (__bf16)o;
        x_out[(size_t)b * 1024 + d] = (f16)o;
    }
}

extern "C" void kernel_launch(void* const* d_in, const int* in_sizes, int n_in,
                              void* d_out, int out_size, void* d_ws, size_t ws_size,
                              hipStream_t stream) {
    const int* trg = (const int*)d_in[0];
    const float* enc = (const float*)d_in[1];
    const float* init_h = (const float*)d_in[2];
    const float* mask = (const float*)d_in[3];
    const float* embW = (const float*)d_in[4];
    const float* Wih = (const float*)d_in[5];
    const float* Whh = (const float*)d_in[6];
    const float* bih = (const float*)d_in[7];
    const float* bhh = (const float*)d_in[8];
    const float* Wa = (const float*)d_in[9];
    const float* Wh = (const float*)d_in[10];
    const float* bh = (const float*)d_in[11];
    const float* Wc = (const float*)d_in[12];
    const float* bc = (const float*)d_in[13];
    const float* blog = (const float*)d_in[14];
    float* out = (float*)d_out;

    char* w = (char*)d_ws;
    auto alloc = [&](size_t bytes) { char* p = w; w += (bytes + 255) & ~(size_t)255; return p; };
    __bf16* embW_bf = (__bf16*)alloc(SN0 * 2);
    __bf16* Wih_bf  = (__bf16*)alloc(SN1 * 2);
    __bf16* enc_bf  = (__bf16*)alloc(SN2 * 2);
    __bf16* Wab_bf  = (__bf16*)alloc(SN3 * 2);
    f16* Wg         = (f16*)alloc(SN4 * 2);
    f16* whf16      = (f16*)alloc(SN5 * 2);
    float* gxe      = (float*)alloc((size_t)T_ * G3_ * B_ * 4);
    f16* epf16      = (f16*)alloc((size_t)BT_ * 512 * 2);
    f16* encWcT     = (f16*)alloc((size_t)32 * 512 * 64 * 2);
    f16* x16        = (f16*)alloc((size_t)2 * 32 * 1024 * 2);
    float* hbuf     = (float*)alloc((size_t)2 * 32 * 512 * 4);
    __bf16* o_bf    = (__bf16*)alloc((size_t)BT_ * D_ * 2);

    // 1) fused setup (converts + packs + state init) — ONE kernel
    {
        size_t total8 = (SN0 + SN1 + SN2 + SN3 + SN4 + SN5 + SN6) / 8;
        int wgs = (int)((total8 + 255) / 256);
        k_setup<<<wgs, 256, 0, stream>>>(embW, Wih, Whh, enc, Wa, Wc, Wh, init_h,
                                         embW_bf, Wih_bf, enc_bf, Wab_bf, Wg, whf16,
                                         x16, hbuf);
    }

    // 2) gxe = emb @ W_ih[:, :512]^T + b_ih -> [t][j][b]; emb rows gathered via trg
    k_gemm_bf16<<<(BT_ / 128) * (G3_ / 128), 256, 0, stream>>>(
        embW_bf, Wih_bf, bih, gxe, nullptr, nullptr, trg, BT_, G3_, 512, 512, 512, 1);

    // 3) [enc_proj | encWc] = enc @ [Wa; Wc]^T -> epf16 (f16 row-major) + encWcT (f16 [b][d][s])
    k_gemm_bf16<<<(BT_ / 128) * (1024 / 128), 256, 0, stream>>>(
        enc_bf, Wab_bf, nullptr, nullptr, epf16, encWcT, nullptr, BT_, 1024, 512, 512, 512, 2);

    // 4) recurrence: 2 kernels per step (R12 structure)
    for (int t = 0; t < T_; ++t) {
        const f16* x_in = x16 + (size_t)(t & 1) * 32 * 1024;
        f16* x_out = x16 + (size_t)((t + 1) & 1) * 32 * 1024;
        const float* h_in = hbuf + (size_t)(t & 1) * 32 * 512;
        float* h_out = hbuf + (size_t)((t + 1) & 1) * 32 * 512;
        k_stepA<<<128, 256, 0, stream>>>(Wg, gxe + (size_t)t * G3_ * B_, bhh,
                                         x_in, x_out, h_in, h_out);
        k_stepB<<<64, 256, 0, stream>>>(whf16, epf16, encWcT, mask, bh, bc,
                                        x_out, o_bf, t);
    }

    // 5) logits = o @ emb_W^T + b_logits
    k_gemm_bf16<<<(BT_ / 128) * (V_ / 128), 256, 0, stream>>>(
        o_bf, embW_bf, blog, out, nullptr, nullptr, nullptr, BT_, V_, 512, 512, 512, 0);
}